// Round 1
// baseline (792.342 us; speedup 1.0000x reference)
//
#include <hip/hip_runtime.h>
#include <hip/hip_bf16.h>

#define N_NODES 50000
#define N_EDGES 800000
#define D_FEAT 128
#define HIDDEN 96
#define N_CLASSES 10
#define N_GRAPHS 64

// ---------------- graph preprocessing ----------------

__global__ void k_init(int* __restrict__ deg_i, int* __restrict__ cursor) {
    int i = blockIdx.x * 256 + threadIdx.x;
    if (i < N_NODES) { deg_i[i] = 0; cursor[i] = 0; }
}

__global__ void k_deg(const int* __restrict__ dst, int* __restrict__ deg_i) {
    int e = blockIdx.x * 256 + threadIdx.x;
    if (e < N_EDGES) atomicAdd(&deg_i[dst[e]], 1);
}

// single-block exclusive scan over 50000 ints + dinv = rsqrt(deg+1)
__global__ __launch_bounds__(1024) void k_scan(const int* __restrict__ deg_i,
                                               int* __restrict__ offs,
                                               float* __restrict__ dinv) {
    __shared__ int part[1024];
    int t = threadIdx.x;
    const int CH = (N_NODES + 1023) / 1024;  // 49
    int base = t * CH;
    int s = 0;
    for (int j = 0; j < CH; ++j) { int i = base + j; if (i < N_NODES) s += deg_i[i]; }
    part[t] = s;
    __syncthreads();
    // Hillis-Steele inclusive scan
    for (int off = 1; off < 1024; off <<= 1) {
        int v = part[t];
        int a = (t >= off) ? part[t - off] : 0;
        __syncthreads();
        part[t] = v + a;
        __syncthreads();
    }
    int run = (t == 0) ? 0 : part[t - 1];
    for (int j = 0; j < CH; ++j) {
        int i = base + j;
        if (i < N_NODES) {
            offs[i] = run;
            run += deg_i[i];
            dinv[i] = rsqrtf((float)(deg_i[i] + 1));  // +1 self-loop
        }
    }
    if (t == 1023) offs[N_NODES] = run;
}

__global__ void k_fill(const int* __restrict__ src, const int* __restrict__ dst,
                       const float* __restrict__ dinv, const int* __restrict__ offs,
                       int* __restrict__ cursor, int* __restrict__ csr_src,
                       float* __restrict__ csr_nrm) {
    int e = blockIdx.x * 256 + threadIdx.x;
    if (e >= N_EDGES) return;
    int s = src[e], d = dst[e];
    int pos = atomicAdd(&cursor[d], 1);
    int slot = offs[d] + pos;
    csr_src[slot] = s;
    csr_nrm[slot] = dinv[s] * dinv[d];
}

// ---------------- per-layer matmul: hw = h @ W  (W is K x 96) ----------------

template <int K>
__global__ __launch_bounds__(256) void k_mm(const float* __restrict__ h,
                                            const float* __restrict__ W,
                                            float* __restrict__ hw) {
    __shared__ float Wl[K * HIDDEN];
    int t = threadIdx.x;
    for (int i = t; i < K * HIDDEN; i += 256) Wl[i] = W[i];
    __syncthreads();
    int id = blockIdx.x * 256 + t;
    int f  = id % HIDDEN;
    int ng = id / HIDDEN;
    int n0 = ng * 4;
    if (n0 >= N_NODES) return;
    const float* h0 = h + (size_t)n0 * K;
    if (n0 + 3 < N_NODES) {
        float a0 = 0.f, a1 = 0.f, a2 = 0.f, a3 = 0.f;
        for (int k = 0; k < K; ++k) {
            float wk = Wl[k * HIDDEN + f];
            a0 += h0[k] * wk;
            a1 += h0[K + k] * wk;
            a2 += h0[2 * K + k] * wk;
            a3 += h0[3 * K + k] * wk;
        }
        hw[(size_t)n0 * HIDDEN + f]       = a0;
        hw[(size_t)(n0 + 1) * HIDDEN + f] = a1;
        hw[(size_t)(n0 + 2) * HIDDEN + f] = a2;
        hw[(size_t)(n0 + 3) * HIDDEN + f] = a3;
    } else {
        for (int j = 0; j < 4; ++j) {
            if (n0 + j < N_NODES) {
                float a = 0.f;
                for (int k = 0; k < K; ++k) a += h[(size_t)(n0 + j) * K + k] * Wl[k * HIDDEN + f];
                hw[(size_t)(n0 + j) * HIDDEN + f] = a;
            }
        }
    }
}

// ------------- aggregation: h_out[n] = relu(b + dinv[n]^2*hw[n] + sum_in hw[s]*nrm) -------------

__global__ __launch_bounds__(256) void k_agg(const float* __restrict__ hw,
                                             const float* __restrict__ dinv,
                                             const int* __restrict__ offs,
                                             const int* __restrict__ csr_src,
                                             const float* __restrict__ csr_nrm,
                                             const float* __restrict__ bias,
                                             float* __restrict__ hout) {
    int id = blockIdx.x * 256 + threadIdx.x;
    if (id >= N_NODES * 24) return;
    int c = id % 24;          // float4 chunk: 24 * 4 = 96 feats
    int n = id / 24;
    const float4* hw4 = (const float4*)hw;
    float di = dinv[n];
    float sl = di * di;
    float4 acc = hw4[n * 24 + c];
    acc.x *= sl; acc.y *= sl; acc.z *= sl; acc.w *= sl;
    int beg = offs[n], end = offs[n + 1];
    for (int i = beg; i < end; ++i) {
        int   s  = csr_src[i];
        float nm = csr_nrm[i];
        float4 v = hw4[s * 24 + c];
        acc.x += v.x * nm; acc.y += v.y * nm; acc.z += v.z * nm; acc.w += v.w * nm;
    }
    float4 b = ((const float4*)bias)[c];
    acc.x = fmaxf(acc.x + b.x, 0.f);
    acc.y = fmaxf(acc.y + b.y, 0.f);
    acc.z = fmaxf(acc.z + b.z, 0.f);
    acc.w = fmaxf(acc.w + b.w, 0.f);
    ((float4*)hout)[n * 24 + c] = acc;
}

// ------------- pooling + MLP head, one block per graph -------------

__global__ __launch_bounds__(128) void k_head(const float* __restrict__ h,
                                              const int* __restrict__ batch,
                                              const float* __restrict__ lw1,
                                              const float* __restrict__ lb1,
                                              const float* __restrict__ lw2,
                                              const float* __restrict__ lb2,
                                              float* __restrict__ out) {
    __shared__ float pooled[HIDDEN];
    __shared__ float zbuf[HIDDEN];
    int g = blockIdx.x;
    int t = threadIdx.x;
    // lower_bound(batch, g) and lower_bound(batch, g+1); batch sorted ascending
    int lo = 0, hi = N_NODES;
    while (lo < hi) { int m = (lo + hi) >> 1; if (batch[m] < g) lo = m + 1; else hi = m; }
    int start = lo;
    lo = start; hi = N_NODES;
    while (lo < hi) { int m = (lo + hi) >> 1; if (batch[m] < g + 1) lo = m + 1; else hi = m; }
    int end = lo;
    float cnt = fmaxf((float)(end - start), 1.f);
    if (t < HIDDEN) {
        float a = 0.f;
        for (int n = start; n < end; ++n) a += h[(size_t)n * HIDDEN + t];
        pooled[t] = a / cnt;
    }
    __syncthreads();
    if (t < HIDDEN) {
        float a = lb1[t];
        for (int k = 0; k < HIDDEN; ++k) a += pooled[k] * lw1[k * HIDDEN + t];
        zbuf[t] = fmaxf(a, 0.f);
    }
    __syncthreads();
    if (t < N_CLASSES) {
        float a = lb2[t];
        for (int k = 0; k < HIDDEN; ++k) a += zbuf[k] * lw2[k * N_CLASSES + t];
        out[g * N_CLASSES + t] = a;
    }
}

// ---------------- launch ----------------

extern "C" void kernel_launch(void* const* d_in, const int* in_sizes, int n_in,
                              void* d_out, int out_size, void* d_ws, size_t ws_size,
                              hipStream_t stream) {
    const float* x   = (const float*)d_in[0];
    const int*   ei  = (const int*)d_in[1];   // [2, E]
    const int*   bat = (const int*)d_in[2];
    const float* W1  = (const float*)d_in[3];
    const float* b1  = (const float*)d_in[4];
    const float* W2  = (const float*)d_in[5];
    const float* b2  = (const float*)d_in[6];
    const float* W3  = (const float*)d_in[7];
    const float* b3  = (const float*)d_in[8];
    const float* lw1 = (const float*)d_in[9];
    const float* lb1 = (const float*)d_in[10];
    const float* lw2 = (const float*)d_in[11];
    const float* lb2 = (const float*)d_in[12];
    float* out = (float*)d_out;

    const int* src = ei;
    const int* dst = ei + N_EDGES;

    // workspace carve-up (256B aligned)
    char* ws = (char*)d_ws;
    size_t off = 0;
    auto alloc = [&](size_t bytes) {
        size_t p = off;
        off = (off + bytes + 255) & ~(size_t)255;
        return p;
    };
    float* dinv    = (float*)(ws + alloc(sizeof(float) * N_NODES));
    int*   deg_i   = (int*)  (ws + alloc(sizeof(int) * N_NODES));
    int*   cursor  = (int*)  (ws + alloc(sizeof(int) * N_NODES));
    int*   offs    = (int*)  (ws + alloc(sizeof(int) * (N_NODES + 1)));
    int*   csr_src = (int*)  (ws + alloc(sizeof(int) * N_EDGES));
    float* csr_nrm = (float*)(ws + alloc(sizeof(float) * N_EDGES));
    float* bufA    = (float*)(ws + alloc(sizeof(float) * (size_t)N_NODES * HIDDEN));
    float* bufB    = (float*)(ws + alloc(sizeof(float) * (size_t)N_NODES * HIDDEN));
    (void)ws_size;

    const int nodeBlocks = (N_NODES + 255) / 256;
    const int edgeBlocks = (N_EDGES + 255) / 256;
    const int mmBlocks   = (HIDDEN * ((N_NODES + 3) / 4) + 255) / 256;
    const int aggBlocks  = (N_NODES * 24 + 255) / 256;

    k_init<<<nodeBlocks, 256, 0, stream>>>(deg_i, cursor);
    k_deg<<<edgeBlocks, 256, 0, stream>>>(dst, deg_i);
    k_scan<<<1, 1024, 0, stream>>>(deg_i, offs, dinv);
    k_fill<<<edgeBlocks, 256, 0, stream>>>(src, dst, dinv, offs, cursor, csr_src, csr_nrm);

    // layer 1: x (K=128)
    k_mm<D_FEAT><<<mmBlocks, 256, 0, stream>>>(x, W1, bufA);
    k_agg<<<aggBlocks, 256, 0, stream>>>(bufA, dinv, offs, csr_src, csr_nrm, b1, bufB);
    // layer 2
    k_mm<HIDDEN><<<mmBlocks, 256, 0, stream>>>(bufB, W2, bufA);
    k_agg<<<aggBlocks, 256, 0, stream>>>(bufA, dinv, offs, csr_src, csr_nrm, b2, bufB);
    // layer 3
    k_mm<HIDDEN><<<mmBlocks, 256, 0, stream>>>(bufB, W3, bufA);
    k_agg<<<aggBlocks, 256, 0, stream>>>(bufA, dinv, offs, csr_src, csr_nrm, b3, bufB);

    k_head<<<N_GRAPHS, 128, 0, stream>>>(bufB, bat, lw1, lb1, lw2, lb2, out);
}

// Round 2
// 603.033 us; speedup vs baseline: 1.3139x; 1.3139x over previous
//
#include <hip/hip_runtime.h>
#include <hip/hip_bf16.h>

#define N_NODES 50000
#define N_EDGES 800000
#define D_FEAT 128
#define HIDDEN 96
#define N_CLASSES 10
#define N_GRAPHS 64
#define POOL_SLICES 16

// ---------------- graph preprocessing ----------------

__global__ void k_init(int* __restrict__ deg_i, int* __restrict__ cursor,
                       float* __restrict__ pooled) {
    int i = blockIdx.x * 256 + threadIdx.x;
    if (i < N_NODES) { deg_i[i] = 0; cursor[i] = 0; }
    if (i < N_GRAPHS * HIDDEN) pooled[i] = 0.f;
}

__global__ void k_deg(const int* __restrict__ dst, int* __restrict__ deg_i) {
    int e = blockIdx.x * 256 + threadIdx.x;
    if (e < N_EDGES) atomicAdd(&deg_i[dst[e]], 1);
}

// single-block exclusive scan over 50000 ints + dinv = rsqrt(deg+1)
__global__ __launch_bounds__(1024) void k_scan(const int* __restrict__ deg_i,
                                               int* __restrict__ offs,
                                               float* __restrict__ dinv) {
    __shared__ int part[1024];
    int t = threadIdx.x;
    const int CH = (N_NODES + 1023) / 1024;  // 49
    int base = t * CH;
    int s = 0;
    for (int j = 0; j < CH; ++j) { int i = base + j; if (i < N_NODES) s += deg_i[i]; }
    part[t] = s;
    __syncthreads();
    // Hillis-Steele inclusive scan
    for (int off = 1; off < 1024; off <<= 1) {
        int v = part[t];
        int a = (t >= off) ? part[t - off] : 0;
        __syncthreads();
        part[t] = v + a;
        __syncthreads();
    }
    int run = (t == 0) ? 0 : part[t - 1];
    for (int j = 0; j < CH; ++j) {
        int i = base + j;
        if (i < N_NODES) {
            offs[i] = run;
            run += deg_i[i];
            dinv[i] = rsqrtf((float)(deg_i[i] + 1));  // +1 self-loop
        }
    }
    if (t == 1023) offs[N_NODES] = run;
}

__global__ void k_fill(const int* __restrict__ src, const int* __restrict__ dst,
                       const float* __restrict__ dinv, const int* __restrict__ offs,
                       int* __restrict__ cursor, int* __restrict__ csr_src,
                       float* __restrict__ csr_nrm) {
    int e = blockIdx.x * 256 + threadIdx.x;
    if (e >= N_EDGES) return;
    int s = src[e], d = dst[e];
    int pos = atomicAdd(&cursor[d], 1);
    int slot = offs[d] + pos;
    csr_src[slot] = s;
    csr_nrm[slot] = dinv[s] * dinv[d];
}

// ---------------- per-layer matmul: hw = h @ W  (W is K x 96) ----------------

template <int K>
__global__ __launch_bounds__(256) void k_mm(const float* __restrict__ h,
                                            const float* __restrict__ W,
                                            float* __restrict__ hw) {
    __shared__ float Wl[K * HIDDEN];
    int t = threadIdx.x;
    for (int i = t; i < K * HIDDEN; i += 256) Wl[i] = W[i];
    __syncthreads();
    int id = blockIdx.x * 256 + t;
    int f  = id % HIDDEN;
    int ng = id / HIDDEN;
    int n0 = ng * 4;
    if (n0 >= N_NODES) return;
    const float* h0 = h + (size_t)n0 * K;
    if (n0 + 3 < N_NODES) {
        float a0 = 0.f, a1 = 0.f, a2 = 0.f, a3 = 0.f;
        for (int k = 0; k < K; ++k) {
            float wk = Wl[k * HIDDEN + f];
            a0 += h0[k] * wk;
            a1 += h0[K + k] * wk;
            a2 += h0[2 * K + k] * wk;
            a3 += h0[3 * K + k] * wk;
        }
        hw[(size_t)n0 * HIDDEN + f]       = a0;
        hw[(size_t)(n0 + 1) * HIDDEN + f] = a1;
        hw[(size_t)(n0 + 2) * HIDDEN + f] = a2;
        hw[(size_t)(n0 + 3) * HIDDEN + f] = a3;
    } else {
        for (int j = 0; j < 4; ++j) {
            if (n0 + j < N_NODES) {
                float a = 0.f;
                for (int k = 0; k < K; ++k) a += h[(size_t)(n0 + j) * K + k] * Wl[k * HIDDEN + f];
                hw[(size_t)(n0 + j) * HIDDEN + f] = a;
            }
        }
    }
}

// ------------- aggregation: h_out[n] = relu(b + dinv[n]^2*hw[n] + sum_in hw[s]*nrm) -------------

__global__ __launch_bounds__(256) void k_agg(const float* __restrict__ hw,
                                             const float* __restrict__ dinv,
                                             const int* __restrict__ offs,
                                             const int* __restrict__ csr_src,
                                             const float* __restrict__ csr_nrm,
                                             const float* __restrict__ bias,
                                             float* __restrict__ hout) {
    int id = blockIdx.x * 256 + threadIdx.x;
    if (id >= N_NODES * 24) return;
    int c = id % 24;          // float4 chunk: 24 * 4 = 96 feats
    int n = id / 24;
    const float4* hw4 = (const float4*)hw;
    float di = dinv[n];
    float sl = di * di;
    float4 acc = hw4[n * 24 + c];
    acc.x *= sl; acc.y *= sl; acc.z *= sl; acc.w *= sl;
    int beg = offs[n], end = offs[n + 1];
    for (int i = beg; i < end; ++i) {
        int   s  = csr_src[i];
        float nm = csr_nrm[i];
        float4 v = hw4[s * 24 + c];
        acc.x += v.x * nm; acc.y += v.y * nm; acc.z += v.z * nm; acc.w += v.w * nm;
    }
    float4 b = ((const float4*)bias)[c];
    acc.x = fmaxf(acc.x + b.x, 0.f);
    acc.y = fmaxf(acc.y + b.y, 0.f);
    acc.z = fmaxf(acc.z + b.z, 0.f);
    acc.w = fmaxf(acc.w + b.w, 0.f);
    ((float4*)hout)[n * 24 + c] = acc;
}

// ------------- parallel mean-pool: 64 graphs x 16 slices -------------

__global__ __launch_bounds__(192) void k_pool(const float* __restrict__ h,
                                              const int* __restrict__ batch,
                                              float* __restrict__ pooled) {
    int g = blockIdx.x / POOL_SLICES;
    int slice = blockIdx.x % POOL_SLICES;
    int t = threadIdx.x;
    int f = t % HIDDEN;
    int j = t / HIDDEN;  // 0 or 1
    // bounds of graph g in sorted batch
    int lo = 0, hi = N_NODES;
    while (lo < hi) { int m = (lo + hi) >> 1; if (batch[m] < g) lo = m + 1; else hi = m; }
    int start = lo;
    hi = N_NODES;
    while (lo < hi) { int m = (lo + hi) >> 1; if (batch[m] < g + 1) lo = m + 1; else hi = m; }
    int end = lo;
    int len = end - start;
    int per = (len + POOL_SLICES - 1) / POOL_SLICES;
    int s0 = start + slice * per;
    int s1 = min(s0 + per, end);
    float acc = 0.f;
    for (int n = s0 + j; n < s1; n += 2) acc += h[(size_t)n * HIDDEN + f];
    atomicAdd(&pooled[g * HIDDEN + f], acc);
}

// ------------- MLP head, one block per graph -------------

__global__ __launch_bounds__(128) void k_head_mlp(const float* __restrict__ pooled_in,
                                                  const int* __restrict__ batch,
                                                  const float* __restrict__ lw1,
                                                  const float* __restrict__ lb1,
                                                  const float* __restrict__ lw2,
                                                  const float* __restrict__ lb2,
                                                  float* __restrict__ out) {
    __shared__ float pooled[HIDDEN];
    __shared__ float zbuf[HIDDEN];
    int g = blockIdx.x;
    int t = threadIdx.x;
    // node count of graph g
    int lo = 0, hi = N_NODES;
    while (lo < hi) { int m = (lo + hi) >> 1; if (batch[m] < g) lo = m + 1; else hi = m; }
    int start = lo;
    hi = N_NODES;
    while (lo < hi) { int m = (lo + hi) >> 1; if (batch[m] < g + 1) lo = m + 1; else hi = m; }
    int end = lo;
    float cnt = fmaxf((float)(end - start), 1.f);
    if (t < HIDDEN) pooled[t] = pooled_in[g * HIDDEN + t] / cnt;
    __syncthreads();
    if (t < HIDDEN) {
        float a = lb1[t];
        for (int k = 0; k < HIDDEN; ++k) a += pooled[k] * lw1[k * HIDDEN + t];
        zbuf[t] = fmaxf(a, 0.f);
    }
    __syncthreads();
    if (t < N_CLASSES) {
        float a = lb2[t];
        for (int k = 0; k < HIDDEN; ++k) a += zbuf[k] * lw2[k * N_CLASSES + t];
        out[g * N_CLASSES + t] = a;
    }
}

// ---------------- launch ----------------

extern "C" void kernel_launch(void* const* d_in, const int* in_sizes, int n_in,
                              void* d_out, int out_size, void* d_ws, size_t ws_size,
                              hipStream_t stream) {
    const float* x   = (const float*)d_in[0];
    const int*   ei  = (const int*)d_in[1];   // [2, E]
    const int*   bat = (const int*)d_in[2];
    const float* W1  = (const float*)d_in[3];
    const float* b1  = (const float*)d_in[4];
    const float* W2  = (const float*)d_in[5];
    const float* b2  = (const float*)d_in[6];
    const float* W3  = (const float*)d_in[7];
    const float* b3  = (const float*)d_in[8];
    const float* lw1 = (const float*)d_in[9];
    const float* lb1 = (const float*)d_in[10];
    const float* lw2 = (const float*)d_in[11];
    const float* lb2 = (const float*)d_in[12];
    float* out = (float*)d_out;

    const int* src = ei;
    const int* dst = ei + N_EDGES;

    // workspace carve-up (256B aligned)
    char* ws = (char*)d_ws;
    size_t off = 0;
    auto alloc = [&](size_t bytes) {
        size_t p = off;
        off = (off + bytes + 255) & ~(size_t)255;
        return p;
    };
    float* dinv    = (float*)(ws + alloc(sizeof(float) * N_NODES));
    int*   deg_i   = (int*)  (ws + alloc(sizeof(int) * N_NODES));
    int*   cursor  = (int*)  (ws + alloc(sizeof(int) * N_NODES));
    int*   offs    = (int*)  (ws + alloc(sizeof(int) * (N_NODES + 1)));
    int*   csr_src = (int*)  (ws + alloc(sizeof(int) * N_EDGES));
    float* csr_nrm = (float*)(ws + alloc(sizeof(float) * N_EDGES));
    float* bufA    = (float*)(ws + alloc(sizeof(float) * (size_t)N_NODES * HIDDEN));
    float* bufB    = (float*)(ws + alloc(sizeof(float) * (size_t)N_NODES * HIDDEN));
    float* pooled  = (float*)(ws + alloc(sizeof(float) * N_GRAPHS * HIDDEN));
    (void)ws_size;

    const int nodeBlocks = (N_NODES + 255) / 256;
    const int edgeBlocks = (N_EDGES + 255) / 256;
    const int mmBlocks   = (HIDDEN * ((N_NODES + 3) / 4) + 255) / 256;
    const int aggBlocks  = (N_NODES * 24 + 255) / 256;

    k_init<<<nodeBlocks, 256, 0, stream>>>(deg_i, cursor, pooled);
    k_deg<<<edgeBlocks, 256, 0, stream>>>(dst, deg_i);
    k_scan<<<1, 1024, 0, stream>>>(deg_i, offs, dinv);
    k_fill<<<edgeBlocks, 256, 0, stream>>>(src, dst, dinv, offs, cursor, csr_src, csr_nrm);

    // layer 1: x (K=128)
    k_mm<D_FEAT><<<mmBlocks, 256, 0, stream>>>(x, W1, bufA);
    k_agg<<<aggBlocks, 256, 0, stream>>>(bufA, dinv, offs, csr_src, csr_nrm, b1, bufB);
    // layer 2
    k_mm<HIDDEN><<<mmBlocks, 256, 0, stream>>>(bufB, W2, bufA);
    k_agg<<<aggBlocks, 256, 0, stream>>>(bufA, dinv, offs, csr_src, csr_nrm, b2, bufB);
    // layer 3
    k_mm<HIDDEN><<<mmBlocks, 256, 0, stream>>>(bufB, W3, bufA);
    k_agg<<<aggBlocks, 256, 0, stream>>>(bufA, dinv, offs, csr_src, csr_nrm, b3, bufB);

    k_pool<<<N_GRAPHS * POOL_SLICES, 192, 0, stream>>>(bufB, bat, pooled);
    k_head_mlp<<<N_GRAPHS, 128, 0, stream>>>(pooled, bat, lw1, lb1, lw2, lb2, out);
}

// Round 3
// 492.604 us; speedup vs baseline: 1.6085x; 1.2242x over previous
//
#include <hip/hip_runtime.h>
#include <hip/hip_bf16.h>

#define N_NODES 50000
#define N_EDGES 800000
#define D_FEAT 128
#define HIDDEN 96
#define N_CLASSES 10
#define N_GRAPHS 64
#define POOL_SLICES 16
#define SCAN_BLOCKS ((N_NODES + 255) / 256)   // 196

// ---------------- graph preprocessing ----------------

__global__ void k_init(int* __restrict__ deg_i, int* __restrict__ cursor,
                       float* __restrict__ pooled) {
    int i = blockIdx.x * 256 + threadIdx.x;
    if (i < N_NODES) { deg_i[i] = 0; cursor[i] = 0; }
    if (i < N_GRAPHS * HIDDEN) pooled[i] = 0.f;
}

__global__ void k_deg(const int* __restrict__ dst, int* __restrict__ deg_i) {
    int e = blockIdx.x * 256 + threadIdx.x;
    if (e < N_EDGES) atomicAdd(&deg_i[dst[e]], 1);
}

// phase 1: per-block sums of deg_i
__global__ __launch_bounds__(256) void k_partial(const int* __restrict__ deg_i,
                                                 int* __restrict__ bsum) {
    __shared__ int wsum[4];
    int i = blockIdx.x * 256 + threadIdx.x;
    int v = (i < N_NODES) ? deg_i[i] : 0;
    for (int o = 32; o > 0; o >>= 1) v += __shfl_down(v, o, 64);
    int lane = threadIdx.x & 63, wid = threadIdx.x >> 6;
    if (lane == 0) wsum[wid] = v;
    __syncthreads();
    if (threadIdx.x == 0) bsum[blockIdx.x] = wsum[0] + wsum[1] + wsum[2] + wsum[3];
}

// phase 2: single small block scans the 196 block sums -> exclusive prefixes
__global__ __launch_bounds__(256) void k_scanblk(const int* __restrict__ bsum,
                                                 int* __restrict__ bpre) {
    __shared__ int s[256];
    int t = threadIdx.x;
    s[t] = (t < SCAN_BLOCKS) ? bsum[t] : 0;
    __syncthreads();
    for (int off = 1; off < 256; off <<= 1) {
        int v = s[t];
        int a = (t >= off) ? s[t - off] : 0;
        __syncthreads();
        s[t] = v + a;
        __syncthreads();
    }
    if (t <= SCAN_BLOCKS) bpre[t] = (t == 0) ? 0 : s[t - 1];  // exclusive
}

// phase 3: local exclusive scan + block prefix -> offs; also dinv
__global__ __launch_bounds__(256) void k_offs(const int* __restrict__ deg_i,
                                              const int* __restrict__ bpre,
                                              int* __restrict__ offs,
                                              float* __restrict__ dinv) {
    __shared__ int s[256];
    int t = threadIdx.x;
    int i = blockIdx.x * 256 + t;
    int d = (i < N_NODES) ? deg_i[i] : 0;
    s[t] = d;
    __syncthreads();
    for (int off = 1; off < 256; off <<= 1) {
        int v = s[t];
        int a = (t >= off) ? s[t - off] : 0;
        __syncthreads();
        s[t] = v + a;
        __syncthreads();
    }
    int incl = s[t];
    int excl = incl - d;
    if (i < N_NODES) {
        int o = bpre[blockIdx.x] + excl;
        offs[i] = o;
        dinv[i] = rsqrtf((float)(d + 1));  // +1 self-loop
        if (i == N_NODES - 1) offs[N_NODES] = o + d;
    }
}

__global__ void k_fill(const int* __restrict__ src, const int* __restrict__ dst,
                       const float* __restrict__ dinv, const int* __restrict__ offs,
                       int* __restrict__ cursor, int* __restrict__ csr_src,
                       float* __restrict__ csr_nrm) {
    int e = blockIdx.x * 256 + threadIdx.x;
    if (e >= N_EDGES) return;
    int s = src[e], d = dst[e];
    int pos = atomicAdd(&cursor[d], 1);
    int slot = offs[d] + pos;
    csr_src[slot] = s;
    csr_nrm[slot] = dinv[s] * dinv[d];
}

// ---------------- per-layer matmul: hw = h @ W  (W is K x 96) ----------------

template <int K>
__global__ __launch_bounds__(256) void k_mm(const float* __restrict__ h,
                                            const float* __restrict__ W,
                                            float* __restrict__ hw) {
    __shared__ float Wl[K * HIDDEN];
    int t = threadIdx.x;
    for (int i = t; i < K * HIDDEN; i += 256) Wl[i] = W[i];
    __syncthreads();
    int id = blockIdx.x * 256 + t;
    int f  = id % HIDDEN;
    int ng = id / HIDDEN;
    int n0 = ng * 4;
    if (n0 >= N_NODES) return;
    const float* h0 = h + (size_t)n0 * K;
    if (n0 + 3 < N_NODES) {
        float a0 = 0.f, a1 = 0.f, a2 = 0.f, a3 = 0.f;
        for (int k = 0; k < K; ++k) {
            float wk = Wl[k * HIDDEN + f];
            a0 += h0[k] * wk;
            a1 += h0[K + k] * wk;
            a2 += h0[2 * K + k] * wk;
            a3 += h0[3 * K + k] * wk;
        }
        hw[(size_t)n0 * HIDDEN + f]       = a0;
        hw[(size_t)(n0 + 1) * HIDDEN + f] = a1;
        hw[(size_t)(n0 + 2) * HIDDEN + f] = a2;
        hw[(size_t)(n0 + 3) * HIDDEN + f] = a3;
    } else {
        for (int j = 0; j < 4; ++j) {
            if (n0 + j < N_NODES) {
                float a = 0.f;
                for (int k = 0; k < K; ++k) a += h[(size_t)(n0 + j) * K + k] * Wl[k * HIDDEN + f];
                hw[(size_t)(n0 + j) * HIDDEN + f] = a;
            }
        }
    }
}

// ------------- aggregation: h_out[n] = relu(b + dinv[n]^2*hw[n] + sum_in hw[s]*nrm) -------------

__global__ __launch_bounds__(256) void k_agg(const float* __restrict__ hw,
                                             const float* __restrict__ dinv,
                                             const int* __restrict__ offs,
                                             const int* __restrict__ csr_src,
                                             const float* __restrict__ csr_nrm,
                                             const float* __restrict__ bias,
                                             float* __restrict__ hout) {
    int id = blockIdx.x * 256 + threadIdx.x;
    if (id >= N_NODES * 24) return;
    int c = id % 24;          // float4 chunk: 24 * 4 = 96 feats
    int n = id / 24;
    const float4* hw4 = (const float4*)hw;
    float di = dinv[n];
    float sl = di * di;
    float4 acc = hw4[n * 24 + c];
    acc.x *= sl; acc.y *= sl; acc.z *= sl; acc.w *= sl;
    int beg = offs[n], end = offs[n + 1];
    for (int i = beg; i < end; ++i) {
        int   s  = csr_src[i];
        float nm = csr_nrm[i];
        float4 v = hw4[s * 24 + c];
        acc.x += v.x * nm; acc.y += v.y * nm; acc.z += v.z * nm; acc.w += v.w * nm;
    }
    float4 b = ((const float4*)bias)[c];
    acc.x = fmaxf(acc.x + b.x, 0.f);
    acc.y = fmaxf(acc.y + b.y, 0.f);
    acc.z = fmaxf(acc.z + b.z, 0.f);
    acc.w = fmaxf(acc.w + b.w, 0.f);
    ((float4*)hout)[n * 24 + c] = acc;
}

// ------------- parallel mean-pool: 64 graphs x 16 slices -------------

__global__ __launch_bounds__(192) void k_pool(const float* __restrict__ h,
                                              const int* __restrict__ batch,
                                              float* __restrict__ pooled) {
    int g = blockIdx.x / POOL_SLICES;
    int slice = blockIdx.x % POOL_SLICES;
    int t = threadIdx.x;
    int f = t % HIDDEN;
    int j = t / HIDDEN;  // 0 or 1
    int lo = 0, hi = N_NODES;
    while (lo < hi) { int m = (lo + hi) >> 1; if (batch[m] < g) lo = m + 1; else hi = m; }
    int start = lo;
    hi = N_NODES;
    while (lo < hi) { int m = (lo + hi) >> 1; if (batch[m] < g + 1) lo = m + 1; else hi = m; }
    int end = lo;
    int len = end - start;
    int per = (len + POOL_SLICES - 1) / POOL_SLICES;
    int s0 = start + slice * per;
    int s1 = min(s0 + per, end);
    float acc = 0.f;
    for (int n = s0 + j; n < s1; n += 2) acc += h[(size_t)n * HIDDEN + f];
    atomicAdd(&pooled[g * HIDDEN + f], acc);
}

// ------------- MLP head, one block per graph -------------

__global__ __launch_bounds__(128) void k_head_mlp(const float* __restrict__ pooled_in,
                                                  const int* __restrict__ batch,
                                                  const float* __restrict__ lw1,
                                                  const float* __restrict__ lb1,
                                                  const float* __restrict__ lw2,
                                                  const float* __restrict__ lb2,
                                                  float* __restrict__ out) {
    __shared__ float pooled[HIDDEN];
    __shared__ float zbuf[HIDDEN];
    int g = blockIdx.x;
    int t = threadIdx.x;
    int lo = 0, hi = N_NODES;
    while (lo < hi) { int m = (lo + hi) >> 1; if (batch[m] < g) lo = m + 1; else hi = m; }
    int start = lo;
    hi = N_NODES;
    while (lo < hi) { int m = (lo + hi) >> 1; if (batch[m] < g + 1) lo = m + 1; else hi = m; }
    int end = lo;
    float cnt = fmaxf((float)(end - start), 1.f);
    if (t < HIDDEN) pooled[t] = pooled_in[g * HIDDEN + t] / cnt;
    __syncthreads();
    if (t < HIDDEN) {
        float a = lb1[t];
        for (int k = 0; k < HIDDEN; ++k) a += pooled[k] * lw1[k * HIDDEN + t];
        zbuf[t] = fmaxf(a, 0.f);
    }
    __syncthreads();
    if (t < N_CLASSES) {
        float a = lb2[t];
        for (int k = 0; k < HIDDEN; ++k) a += zbuf[k] * lw2[k * N_CLASSES + t];
        out[g * N_CLASSES + t] = a;
    }
}

// ---------------- launch ----------------

extern "C" void kernel_launch(void* const* d_in, const int* in_sizes, int n_in,
                              void* d_out, int out_size, void* d_ws, size_t ws_size,
                              hipStream_t stream) {
    const float* x   = (const float*)d_in[0];
    const int*   ei  = (const int*)d_in[1];   // [2, E]
    const int*   bat = (const int*)d_in[2];
    const float* W1  = (const float*)d_in[3];
    const float* b1  = (const float*)d_in[4];
    const float* W2  = (const float*)d_in[5];
    const float* b2  = (const float*)d_in[6];
    const float* W3  = (const float*)d_in[7];
    const float* b3  = (const float*)d_in[8];
    const float* lw1 = (const float*)d_in[9];
    const float* lb1 = (const float*)d_in[10];
    const float* lw2 = (const float*)d_in[11];
    const float* lb2 = (const float*)d_in[12];
    float* out = (float*)d_out;

    const int* src = ei;
    const int* dst = ei + N_EDGES;

    // workspace carve-up (256B aligned)
    char* ws = (char*)d_ws;
    size_t off = 0;
    auto alloc = [&](size_t bytes) {
        size_t p = off;
        off = (off + bytes + 255) & ~(size_t)255;
        return p;
    };
    float* dinv    = (float*)(ws + alloc(sizeof(float) * N_NODES));
    int*   deg_i   = (int*)  (ws + alloc(sizeof(int) * N_NODES));
    int*   cursor  = (int*)  (ws + alloc(sizeof(int) * N_NODES));
    int*   offs    = (int*)  (ws + alloc(sizeof(int) * (N_NODES + 1)));
    int*   bsum    = (int*)  (ws + alloc(sizeof(int) * (SCAN_BLOCKS + 1)));
    int*   bpre    = (int*)  (ws + alloc(sizeof(int) * (SCAN_BLOCKS + 1)));
    int*   csr_src = (int*)  (ws + alloc(sizeof(int) * N_EDGES));
    float* csr_nrm = (float*)(ws + alloc(sizeof(float) * N_EDGES));
    float* bufA    = (float*)(ws + alloc(sizeof(float) * (size_t)N_NODES * HIDDEN));
    float* bufB    = (float*)(ws + alloc(sizeof(float) * (size_t)N_NODES * HIDDEN));
    float* pooled  = (float*)(ws + alloc(sizeof(float) * N_GRAPHS * HIDDEN));
    (void)ws_size;

    const int nodeBlocks = (N_NODES + 255) / 256;
    const int edgeBlocks = (N_EDGES + 255) / 256;
    const int mmBlocks   = (HIDDEN * ((N_NODES + 3) / 4) + 255) / 256;
    const int aggBlocks  = (N_NODES * 24 + 255) / 256;

    k_init<<<nodeBlocks, 256, 0, stream>>>(deg_i, cursor, pooled);
    k_deg<<<edgeBlocks, 256, 0, stream>>>(dst, deg_i);
    k_partial<<<SCAN_BLOCKS, 256, 0, stream>>>(deg_i, bsum);
    k_scanblk<<<1, 256, 0, stream>>>(bsum, bpre);
    k_offs<<<SCAN_BLOCKS, 256, 0, stream>>>(deg_i, bpre, offs, dinv);
    k_fill<<<edgeBlocks, 256, 0, stream>>>(src, dst, dinv, offs, cursor, csr_src, csr_nrm);

    // layer 1: x (K=128)
    k_mm<D_FEAT><<<mmBlocks, 256, 0, stream>>>(x, W1, bufA);
    k_agg<<<aggBlocks, 256, 0, stream>>>(bufA, dinv, offs, csr_src, csr_nrm, b1, bufB);
    // layer 2
    k_mm<HIDDEN><<<mmBlocks, 256, 0, stream>>>(bufB, W2, bufA);
    k_agg<<<aggBlocks, 256, 0, stream>>>(bufA, dinv, offs, csr_src, csr_nrm, b2, bufB);
    // layer 3
    k_mm<HIDDEN><<<mmBlocks, 256, 0, stream>>>(bufB, W3, bufA);
    k_agg<<<aggBlocks, 256, 0, stream>>>(bufA, dinv, offs, csr_src, csr_nrm, b3, bufB);

    k_pool<<<N_GRAPHS * POOL_SLICES, 192, 0, stream>>>(bufB, bat, pooled);
    k_head_mlp<<<N_GRAPHS, 128, 0, stream>>>(pooled, bat, lw1, lb1, lw2, lb2, out);
}

// Round 4
// 385.046 us; speedup vs baseline: 2.0578x; 1.2793x over previous
//
#include <hip/hip_runtime.h>
#include <hip/hip_bf16.h>

#define N_NODES 50000
#define N_EDGES 800000
#define D_FEAT 128
#define HIDDEN 96
#define N_CLASSES 10
#define N_GRAPHS 64
#define POOL_SLICES 16
#define SCAN_BLOCKS ((N_NODES + 255) / 256)   // 196

// ---------------- graph preprocessing ----------------

__global__ void k_init(int* __restrict__ deg_i, int* __restrict__ cursor,
                       float* __restrict__ pooled) {
    int i = blockIdx.x * 256 + threadIdx.x;
    if (i < N_NODES) { deg_i[i] = 0; cursor[i] = 0; }
    if (i < N_GRAPHS * HIDDEN) pooled[i] = 0.f;
}

__global__ void k_deg(const int* __restrict__ dst, int* __restrict__ deg_i) {
    int e = blockIdx.x * 256 + threadIdx.x;
    if (e < N_EDGES) atomicAdd(&deg_i[dst[e]], 1);
}

// phase 1: per-block sums of deg_i
__global__ __launch_bounds__(256) void k_partial(const int* __restrict__ deg_i,
                                                 int* __restrict__ bsum) {
    __shared__ int wsum[4];
    int i = blockIdx.x * 256 + threadIdx.x;
    int v = (i < N_NODES) ? deg_i[i] : 0;
    for (int o = 32; o > 0; o >>= 1) v += __shfl_down(v, o, 64);
    int lane = threadIdx.x & 63, wid = threadIdx.x >> 6;
    if (lane == 0) wsum[wid] = v;
    __syncthreads();
    if (threadIdx.x == 0) bsum[blockIdx.x] = wsum[0] + wsum[1] + wsum[2] + wsum[3];
}

// phase 2: single small block scans the block sums -> exclusive prefixes
__global__ __launch_bounds__(256) void k_scanblk(const int* __restrict__ bsum,
                                                 int* __restrict__ bpre) {
    __shared__ int s[256];
    int t = threadIdx.x;
    s[t] = (t < SCAN_BLOCKS) ? bsum[t] : 0;
    __syncthreads();
    for (int off = 1; off < 256; off <<= 1) {
        int v = s[t];
        int a = (t >= off) ? s[t - off] : 0;
        __syncthreads();
        s[t] = v + a;
        __syncthreads();
    }
    if (t <= SCAN_BLOCKS) bpre[t] = (t == 0) ? 0 : s[t - 1];  // exclusive
}

// phase 3: local exclusive scan + block prefix -> offs; also dinv
__global__ __launch_bounds__(256) void k_offs(const int* __restrict__ deg_i,
                                              const int* __restrict__ bpre,
                                              int* __restrict__ offs,
                                              float* __restrict__ dinv) {
    __shared__ int s[256];
    int t = threadIdx.x;
    int i = blockIdx.x * 256 + t;
    int d = (i < N_NODES) ? deg_i[i] : 0;
    s[t] = d;
    __syncthreads();
    for (int off = 1; off < 256; off <<= 1) {
        int v = s[t];
        int a = (t >= off) ? s[t - off] : 0;
        __syncthreads();
        s[t] = v + a;
        __syncthreads();
    }
    int incl = s[t];
    int excl = incl - d;
    if (i < N_NODES) {
        int o = bpre[blockIdx.x] + excl;
        offs[i] = o;
        dinv[i] = rsqrtf((float)(d + 1));  // +1 self-loop
        if (i == N_NODES - 1) offs[N_NODES] = o + d;
    }
}

__global__ void k_fill(const int* __restrict__ src, const int* __restrict__ dst,
                       const float* __restrict__ dinv, const int* __restrict__ offs,
                       int* __restrict__ cursor, int* __restrict__ csr_src,
                       float* __restrict__ csr_nrm) {
    int e = blockIdx.x * 256 + threadIdx.x;
    if (e >= N_EDGES) return;
    int s = src[e], d = dst[e];
    int pos = atomicAdd(&cursor[d], 1);
    int slot = offs[d] + pos;
    csr_src[slot] = s;
    csr_nrm[slot] = dinv[s] * dinv[d];
}

// ---------------- per-layer matmul: hw = h @ W  (W is K x 96) ----------------
// Register-tiled: block = 256 thr, tile = 128 nodes x 96 f; thread = 4 nodes x 12 f.

#define FMA12(HQ, W0, W1, W2, R)                                        \
    acc[R][0].x += (HQ) * (W0).x; acc[R][0].y += (HQ) * (W0).y;         \
    acc[R][0].z += (HQ) * (W0).z; acc[R][0].w += (HQ) * (W0).w;         \
    acc[R][1].x += (HQ) * (W1).x; acc[R][1].y += (HQ) * (W1).y;         \
    acc[R][1].z += (HQ) * (W1).z; acc[R][1].w += (HQ) * (W1).w;         \
    acc[R][2].x += (HQ) * (W2).x; acc[R][2].y += (HQ) * (W2).y;         \
    acc[R][2].z += (HQ) * (W2).z; acc[R][2].w += (HQ) * (W2).w;

#define QSTEP(COMP)                                                     \
    {                                                                   \
        float4 w0 = Wl[kw + jc + 0];                                    \
        float4 w1 = Wl[kw + jc + 1];                                    \
        float4 w2 = Wl[kw + jc + 2];                                    \
        FMA12(hv[0].COMP, w0, w1, w2, 0)                                \
        FMA12(hv[1].COMP, w0, w1, w2, 1)                                \
        FMA12(hv[2].COMP, w0, w1, w2, 2)                                \
        FMA12(hv[3].COMP, w0, w1, w2, 3)                                \
        kw += 24;                                                       \
    }

template <int K>
__global__ __launch_bounds__(256) void k_mm(const float* __restrict__ h,
                                            const float* __restrict__ W,
                                            float* __restrict__ hw) {
    constexpr int K4 = K / 4;
    __shared__ float4 Wl[K * 24];  // K x 96 floats
    int t = threadIdx.x;
    const float4* W4 = (const float4*)W;
    for (int i = t; i < K * 24; i += 256) Wl[i] = W4[i];
    __syncthreads();

    int i = t & 31, j = t >> 5;
    int n0 = blockIdx.x * 128 + i * 4;
    int jc = j * 3;  // float4 offset of f0 = j*12
    const float4* h4 = (const float4*)h;
    size_t rb[4];
    #pragma unroll
    for (int r = 0; r < 4; ++r) {
        int n = n0 + r;
        if (n > N_NODES - 1) n = N_NODES - 1;
        rb[r] = (size_t)n * K4;
    }
    float4 acc[4][3];
    #pragma unroll
    for (int r = 0; r < 4; ++r)
        #pragma unroll
        for (int c = 0; c < 3; ++c) acc[r][c] = make_float4(0.f, 0.f, 0.f, 0.f);

    for (int kk = 0; kk < K4; ++kk) {
        float4 hv[4];
        #pragma unroll
        for (int r = 0; r < 4; ++r) hv[r] = h4[rb[r] + kk];
        int kw = 4 * kk * 24;
        QSTEP(x)
        QSTEP(y)
        QSTEP(z)
        QSTEP(w)
    }

    float4* hw4 = (float4*)hw;
    #pragma unroll
    for (int r = 0; r < 4; ++r) {
        int n = n0 + r;
        if (n < N_NODES) {
            size_t b = (size_t)n * 24 + jc;
            hw4[b]     = acc[r][0];
            hw4[b + 1] = acc[r][1];
            hw4[b + 2] = acc[r][2];
        }
    }
}

// ------------- aggregation: h_out[n] = relu(b + dinv[n]^2*hw[n] + sum_in hw[s]*nrm) -------------

__global__ __launch_bounds__(256) void k_agg(const float* __restrict__ hw,
                                             const float* __restrict__ dinv,
                                             const int* __restrict__ offs,
                                             const int* __restrict__ csr_src,
                                             const float* __restrict__ csr_nrm,
                                             const float* __restrict__ bias,
                                             float* __restrict__ hout) {
    int id = blockIdx.x * 256 + threadIdx.x;
    if (id >= N_NODES * 24) return;
    int c = id % 24;          // float4 chunk: 24 * 4 = 96 feats
    int n = id / 24;
    const float4* hw4 = (const float4*)hw;
    float di = dinv[n];
    float sl = di * di;
    float4 acc = hw4[n * 24 + c];
    acc.x *= sl; acc.y *= sl; acc.z *= sl; acc.w *= sl;
    int beg = offs[n], end = offs[n + 1];
    for (int i = beg; i < end; ++i) {
        int   s  = csr_src[i];
        float nm = csr_nrm[i];
        float4 v = hw4[s * 24 + c];
        acc.x += v.x * nm; acc.y += v.y * nm; acc.z += v.z * nm; acc.w += v.w * nm;
    }
    float4 b = ((const float4*)bias)[c];
    acc.x = fmaxf(acc.x + b.x, 0.f);
    acc.y = fmaxf(acc.y + b.y, 0.f);
    acc.z = fmaxf(acc.z + b.z, 0.f);
    acc.w = fmaxf(acc.w + b.w, 0.f);
    ((float4*)hout)[n * 24 + c] = acc;
}

// ------------- parallel mean-pool: 64 graphs x 16 slices -------------

__global__ __launch_bounds__(192) void k_pool(const float* __restrict__ h,
                                              const int* __restrict__ batch,
                                              float* __restrict__ pooled) {
    int g = blockIdx.x / POOL_SLICES;
    int slice = blockIdx.x % POOL_SLICES;
    int t = threadIdx.x;
    int f = t % HIDDEN;
    int j = t / HIDDEN;  // 0 or 1
    int lo = 0, hi = N_NODES;
    while (lo < hi) { int m = (lo + hi) >> 1; if (batch[m] < g) lo = m + 1; else hi = m; }
    int start = lo;
    hi = N_NODES;
    while (lo < hi) { int m = (lo + hi) >> 1; if (batch[m] < g + 1) lo = m + 1; else hi = m; }
    int end = lo;
    int len = end - start;
    int per = (len + POOL_SLICES - 1) / POOL_SLICES;
    int s0 = start + slice * per;
    int s1 = min(s0 + per, end);
    float acc = 0.f;
    for (int n = s0 + j; n < s1; n += 2) acc += h[(size_t)n * HIDDEN + f];
    atomicAdd(&pooled[g * HIDDEN + f], acc);
}

// ------------- MLP head, one block per graph -------------

__global__ __launch_bounds__(128) void k_head_mlp(const float* __restrict__ pooled_in,
                                                  const int* __restrict__ batch,
                                                  const float* __restrict__ lw1,
                                                  const float* __restrict__ lb1,
                                                  const float* __restrict__ lw2,
                                                  const float* __restrict__ lb2,
                                                  float* __restrict__ out) {
    __shared__ float pooled[HIDDEN];
    __shared__ float zbuf[HIDDEN];
    int g = blockIdx.x;
    int t = threadIdx.x;
    int lo = 0, hi = N_NODES;
    while (lo < hi) { int m = (lo + hi) >> 1; if (batch[m] < g) lo = m + 1; else hi = m; }
    int start = lo;
    hi = N_NODES;
    while (lo < hi) { int m = (lo + hi) >> 1; if (batch[m] < g + 1) lo = m + 1; else hi = m; }
    int end = lo;
    float cnt = fmaxf((float)(end - start), 1.f);
    if (t < HIDDEN) pooled[t] = pooled_in[g * HIDDEN + t] / cnt;
    __syncthreads();
    if (t < HIDDEN) {
        float a = lb1[t];
        for (int k = 0; k < HIDDEN; ++k) a += pooled[k] * lw1[k * HIDDEN + t];
        zbuf[t] = fmaxf(a, 0.f);
    }
    __syncthreads();
    if (t < N_CLASSES) {
        float a = lb2[t];
        for (int k = 0; k < HIDDEN; ++k) a += zbuf[k] * lw2[k * N_CLASSES + t];
        out[g * N_CLASSES + t] = a;
    }
}

// ---------------- launch ----------------

extern "C" void kernel_launch(void* const* d_in, const int* in_sizes, int n_in,
                              void* d_out, int out_size, void* d_ws, size_t ws_size,
                              hipStream_t stream) {
    const float* x   = (const float*)d_in[0];
    const int*   ei  = (const int*)d_in[1];   // [2, E]
    const int*   bat = (const int*)d_in[2];
    const float* W1  = (const float*)d_in[3];
    const float* b1  = (const float*)d_in[4];
    const float* W2  = (const float*)d_in[5];
    const float* b2  = (const float*)d_in[6];
    const float* W3  = (const float*)d_in[7];
    const float* b3  = (const float*)d_in[8];
    const float* lw1 = (const float*)d_in[9];
    const float* lb1 = (const float*)d_in[10];
    const float* lw2 = (const float*)d_in[11];
    const float* lb2 = (const float*)d_in[12];
    float* out = (float*)d_out;

    const int* src = ei;
    const int* dst = ei + N_EDGES;

    // workspace carve-up (256B aligned)
    char* ws = (char*)d_ws;
    size_t off = 0;
    auto alloc = [&](size_t bytes) {
        size_t p = off;
        off = (off + bytes + 255) & ~(size_t)255;
        return p;
    };
    float* dinv    = (float*)(ws + alloc(sizeof(float) * N_NODES));
    int*   deg_i   = (int*)  (ws + alloc(sizeof(int) * N_NODES));
    int*   cursor  = (int*)  (ws + alloc(sizeof(int) * N_NODES));
    int*   offs    = (int*)  (ws + alloc(sizeof(int) * (N_NODES + 1)));
    int*   bsum    = (int*)  (ws + alloc(sizeof(int) * (SCAN_BLOCKS + 1)));
    int*   bpre    = (int*)  (ws + alloc(sizeof(int) * (SCAN_BLOCKS + 1)));
    int*   csr_src = (int*)  (ws + alloc(sizeof(int) * N_EDGES));
    float* csr_nrm = (float*)(ws + alloc(sizeof(float) * N_EDGES));
    float* bufA    = (float*)(ws + alloc(sizeof(float) * (size_t)N_NODES * HIDDEN));
    float* bufB    = (float*)(ws + alloc(sizeof(float) * (size_t)N_NODES * HIDDEN));
    float* pooled  = (float*)(ws + alloc(sizeof(float) * N_GRAPHS * HIDDEN));
    (void)ws_size;

    const int nodeBlocks = (N_NODES + 255) / 256;
    const int edgeBlocks = (N_EDGES + 255) / 256;
    const int mmBlocks   = (N_NODES + 127) / 128;   // 391
    const int aggBlocks  = (N_NODES * 24 + 255) / 256;

    k_init<<<nodeBlocks, 256, 0, stream>>>(deg_i, cursor, pooled);
    k_deg<<<edgeBlocks, 256, 0, stream>>>(dst, deg_i);
    k_partial<<<SCAN_BLOCKS, 256, 0, stream>>>(deg_i, bsum);
    k_scanblk<<<1, 256, 0, stream>>>(bsum, bpre);
    k_offs<<<SCAN_BLOCKS, 256, 0, stream>>>(deg_i, bpre, offs, dinv);
    k_fill<<<edgeBlocks, 256, 0, stream>>>(src, dst, dinv, offs, cursor, csr_src, csr_nrm);

    // layer 1: x (K=128)
    k_mm<D_FEAT><<<mmBlocks, 256, 0, stream>>>(x, W1, bufA);
    k_agg<<<aggBlocks, 256, 0, stream>>>(bufA, dinv, offs, csr_src, csr_nrm, b1, bufB);
    // layer 2
    k_mm<HIDDEN><<<mmBlocks, 256, 0, stream>>>(bufB, W2, bufA);
    k_agg<<<aggBlocks, 256, 0, stream>>>(bufA, dinv, offs, csr_src, csr_nrm, b2, bufB);
    // layer 3
    k_mm<HIDDEN><<<mmBlocks, 256, 0, stream>>>(bufB, W3, bufA);
    k_agg<<<aggBlocks, 256, 0, stream>>>(bufA, dinv, offs, csr_src, csr_nrm, b3, bufB);

    k_pool<<<N_GRAPHS * POOL_SLICES, 192, 0, stream>>>(bufB, bat, pooled);
    k_head_mlp<<<N_GRAPHS, 128, 0, stream>>>(pooled, bat, lw1, lb1, lw2, lb2, out);
}

// Round 5
// 325.988 us; speedup vs baseline: 2.4306x; 1.1812x over previous
//
#include <hip/hip_runtime.h>
#include <hip/hip_bf16.h>

#define N_NODES 50000
#define N_EDGES 800000
#define D_FEAT 128
#define HIDDEN 96
#define N_CLASSES 10
#define N_GRAPHS 64
#define POOL_SLICES 16
#define SCAN_BLOCKS ((N_NODES + 255) / 256)   // 196

// ---------------- graph preprocessing ----------------

__global__ void k_init(int* __restrict__ deg_i, float* __restrict__ pooled) {
    int i = blockIdx.x * 256 + threadIdx.x;
    if (i < N_NODES) deg_i[i] = 0;
    if (i < N_GRAPHS * HIDDEN) pooled[i] = 0.f;
}

// histogram + per-edge rank (atomicAdd returns old value = rank within dst)
__global__ void k_deg(const int* __restrict__ dst, int* __restrict__ deg_i,
                      int* __restrict__ rank) {
    int e = blockIdx.x * 256 + threadIdx.x;
    if (e < N_EDGES) rank[e] = atomicAdd(&deg_i[dst[e]], 1);
}

// phase 1: per-block sums of deg_i
__global__ __launch_bounds__(256) void k_partial(const int* __restrict__ deg_i,
                                                 int* __restrict__ bsum) {
    __shared__ int wsum[4];
    int i = blockIdx.x * 256 + threadIdx.x;
    int v = (i < N_NODES) ? deg_i[i] : 0;
    for (int o = 32; o > 0; o >>= 1) v += __shfl_down(v, o, 64);
    int lane = threadIdx.x & 63, wid = threadIdx.x >> 6;
    if (lane == 0) wsum[wid] = v;
    __syncthreads();
    if (threadIdx.x == 0) bsum[blockIdx.x] = wsum[0] + wsum[1] + wsum[2] + wsum[3];
}

// phase 2: single small block scans the block sums -> exclusive prefixes
__global__ __launch_bounds__(256) void k_scanblk(const int* __restrict__ bsum,
                                                 int* __restrict__ bpre) {
    __shared__ int s[256];
    int t = threadIdx.x;
    s[t] = (t < SCAN_BLOCKS) ? bsum[t] : 0;
    __syncthreads();
    for (int off = 1; off < 256; off <<= 1) {
        int v = s[t];
        int a = (t >= off) ? s[t - off] : 0;
        __syncthreads();
        s[t] = v + a;
        __syncthreads();
    }
    if (t <= SCAN_BLOCKS) bpre[t] = (t == 0) ? 0 : s[t - 1];  // exclusive
}

// phase 3: local exclusive scan + block prefix -> offs; also dinv
__global__ __launch_bounds__(256) void k_offs(const int* __restrict__ deg_i,
                                              const int* __restrict__ bpre,
                                              int* __restrict__ offs,
                                              float* __restrict__ dinv) {
    __shared__ int s[256];
    int t = threadIdx.x;
    int i = blockIdx.x * 256 + t;
    int d = (i < N_NODES) ? deg_i[i] : 0;
    s[t] = d;
    __syncthreads();
    for (int off = 1; off < 256; off <<= 1) {
        int v = s[t];
        int a = (t >= off) ? s[t - off] : 0;
        __syncthreads();
        s[t] = v + a;
        __syncthreads();
    }
    int incl = s[t];
    int excl = incl - d;
    if (i < N_NODES) {
        int o = bpre[blockIdx.x] + excl;
        offs[i] = o;
        dinv[i] = rsqrtf((float)(d + 1));  // +1 self-loop
        if (i == N_NODES - 1) offs[N_NODES] = o + d;
    }
}

// atomic-free CSR fill: slot = offs[dst] + rank
__global__ void k_fill(const int* __restrict__ src, const int* __restrict__ dst,
                       const int* __restrict__ rank, const int* __restrict__ offs,
                       int* __restrict__ csr_src) {
    int e = blockIdx.x * 256 + threadIdx.x;
    if (e >= N_EDGES) return;
    csr_src[offs[dst[e]] + rank[e]] = src[e];
}

// ---------------- per-layer matmul: hws = (h @ W) * dinv  (W is K x 96) ----------------
// Register-tiled: block = 256 thr, tile = 128 nodes x 96 f; thread = 4 nodes x 12 f.

#define FMA12(HQ, W0, W1, W2, R)                                        \
    acc[R][0].x += (HQ) * (W0).x; acc[R][0].y += (HQ) * (W0).y;         \
    acc[R][0].z += (HQ) * (W0).z; acc[R][0].w += (HQ) * (W0).w;         \
    acc[R][1].x += (HQ) * (W1).x; acc[R][1].y += (HQ) * (W1).y;         \
    acc[R][1].z += (HQ) * (W1).z; acc[R][1].w += (HQ) * (W1).w;         \
    acc[R][2].x += (HQ) * (W2).x; acc[R][2].y += (HQ) * (W2).y;         \
    acc[R][2].z += (HQ) * (W2).z; acc[R][2].w += (HQ) * (W2).w;

#define QSTEP(COMP)                                                     \
    {                                                                   \
        float4 w0 = Wl[kw + jc + 0];                                    \
        float4 w1 = Wl[kw + jc + 1];                                    \
        float4 w2 = Wl[kw + jc + 2];                                    \
        FMA12(hv[0].COMP, w0, w1, w2, 0)                                \
        FMA12(hv[1].COMP, w0, w1, w2, 1)                                \
        FMA12(hv[2].COMP, w0, w1, w2, 2)                                \
        FMA12(hv[3].COMP, w0, w1, w2, 3)                                \
        kw += 24;                                                       \
    }

template <int K>
__global__ __launch_bounds__(256) void k_mm(const float* __restrict__ h,
                                            const float* __restrict__ W,
                                            const float* __restrict__ dinv,
                                            float* __restrict__ hws) {
    constexpr int K4 = K / 4;
    __shared__ float4 Wl[K * 24];  // K x 96 floats
    int t = threadIdx.x;
    const float4* W4 = (const float4*)W;
    for (int i = t; i < K * 24; i += 256) Wl[i] = W4[i];
    __syncthreads();

    int i = t & 31, j = t >> 5;
    int n0 = blockIdx.x * 128 + i * 4;
    int jc = j * 3;  // float4 offset of f0 = j*12
    const float4* h4 = (const float4*)h;
    size_t rb[4];
    #pragma unroll
    for (int r = 0; r < 4; ++r) {
        int n = n0 + r;
        if (n > N_NODES - 1) n = N_NODES - 1;
        rb[r] = (size_t)n * K4;
    }
    float4 acc[4][3];
    #pragma unroll
    for (int r = 0; r < 4; ++r)
        #pragma unroll
        for (int c = 0; c < 3; ++c) acc[r][c] = make_float4(0.f, 0.f, 0.f, 0.f);

    for (int kk = 0; kk < K4; ++kk) {
        float4 hv[4];
        #pragma unroll
        for (int r = 0; r < 4; ++r) hv[r] = h4[rb[r] + kk];
        int kw = 4 * kk * 24;
        QSTEP(x)
        QSTEP(y)
        QSTEP(z)
        QSTEP(w)
    }

    float4* hw4 = (float4*)hws;
    #pragma unroll
    for (int r = 0; r < 4; ++r) {
        int n = n0 + r;
        if (n < N_NODES) {
            float dv = dinv[n];
            size_t b = (size_t)n * 24 + jc;
            #pragma unroll
            for (int c = 0; c < 3; ++c) {
                float4 a = acc[r][c];
                a.x *= dv; a.y *= dv; a.z *= dv; a.w *= dv;
                hw4[b + c] = a;
            }
        }
    }
}

// ------------- aggregation: h_out[n] = relu(b + dinv[n]*(hws[n] + sum_in hws[s])) -------------

__global__ __launch_bounds__(256) void k_agg(const float* __restrict__ hws,
                                             const float* __restrict__ dinv,
                                             const int* __restrict__ offs,
                                             const int* __restrict__ csr_src,
                                             const float* __restrict__ bias,
                                             float* __restrict__ hout) {
    int id = blockIdx.x * 256 + threadIdx.x;
    if (id >= N_NODES * 24) return;
    int c = id % 24;          // float4 chunk: 24 * 4 = 96 feats
    int n = id / 24;
    const float4* hw4 = (const float4*)hws;
    float4 acc = hw4[n * 24 + c];   // self-loop term (already scaled by dinv[n])
    int beg = offs[n], end = offs[n + 1];
    int i = beg;
    for (; i + 2 <= end; i += 2) {
        int s0 = csr_src[i];
        int s1 = csr_src[i + 1];
        float4 v0 = hw4[s0 * 24 + c];
        float4 v1 = hw4[s1 * 24 + c];
        acc.x += v0.x + v1.x; acc.y += v0.y + v1.y;
        acc.z += v0.z + v1.z; acc.w += v0.w + v1.w;
    }
    if (i < end) {
        int s0 = csr_src[i];
        float4 v0 = hw4[s0 * 24 + c];
        acc.x += v0.x; acc.y += v0.y; acc.z += v0.z; acc.w += v0.w;
    }
    float di = dinv[n];
    float4 b = ((const float4*)bias)[c];
    acc.x = fmaxf(acc.x * di + b.x, 0.f);
    acc.y = fmaxf(acc.y * di + b.y, 0.f);
    acc.z = fmaxf(acc.z * di + b.z, 0.f);
    acc.w = fmaxf(acc.w * di + b.w, 0.f);
    ((float4*)hout)[n * 24 + c] = acc;
}

// ------------- parallel mean-pool: 64 graphs x 16 slices -------------

__global__ __launch_bounds__(192) void k_pool(const float* __restrict__ h,
                                              const int* __restrict__ batch,
                                              float* __restrict__ pooled) {
    int g = blockIdx.x / POOL_SLICES;
    int slice = blockIdx.x % POOL_SLICES;
    int t = threadIdx.x;
    int f = t % HIDDEN;
    int j = t / HIDDEN;  // 0 or 1
    int lo = 0, hi = N_NODES;
    while (lo < hi) { int m = (lo + hi) >> 1; if (batch[m] < g) lo = m + 1; else hi = m; }
    int start = lo;
    hi = N_NODES;
    while (lo < hi) { int m = (lo + hi) >> 1; if (batch[m] < g + 1) lo = m + 1; else hi = m; }
    int end = lo;
    int len = end - start;
    int per = (len + POOL_SLICES - 1) / POOL_SLICES;
    int s0 = start + slice * per;
    int s1 = min(s0 + per, end);
    float acc = 0.f;
    for (int n = s0 + j; n < s1; n += 2) acc += h[(size_t)n * HIDDEN + f];
    atomicAdd(&pooled[g * HIDDEN + f], acc);
}

// ------------- MLP head, one block per graph -------------

__global__ __launch_bounds__(128) void k_head_mlp(const float* __restrict__ pooled_in,
                                                  const int* __restrict__ batch,
                                                  const float* __restrict__ lw1,
                                                  const float* __restrict__ lb1,
                                                  const float* __restrict__ lw2,
                                                  const float* __restrict__ lb2,
                                                  float* __restrict__ out) {
    __shared__ float pooled[HIDDEN];
    __shared__ float zbuf[HIDDEN];
    int g = blockIdx.x;
    int t = threadIdx.x;
    int lo = 0, hi = N_NODES;
    while (lo < hi) { int m = (lo + hi) >> 1; if (batch[m] < g) lo = m + 1; else hi = m; }
    int start = lo;
    hi = N_NODES;
    while (lo < hi) { int m = (lo + hi) >> 1; if (batch[m] < g + 1) lo = m + 1; else hi = m; }
    int end = lo;
    float cnt = fmaxf((float)(end - start), 1.f);
    if (t < HIDDEN) pooled[t] = pooled_in[g * HIDDEN + t] / cnt;
    __syncthreads();
    if (t < HIDDEN) {
        float a = lb1[t];
        for (int k = 0; k < HIDDEN; ++k) a += pooled[k] * lw1[k * HIDDEN + t];
        zbuf[t] = fmaxf(a, 0.f);
    }
    __syncthreads();
    if (t < N_CLASSES) {
        float a = lb2[t];
        for (int k = 0; k < HIDDEN; ++k) a += zbuf[k] * lw2[k * N_CLASSES + t];
        out[g * N_CLASSES + t] = a;
    }
}

// ---------------- launch ----------------

extern "C" void kernel_launch(void* const* d_in, const int* in_sizes, int n_in,
                              void* d_out, int out_size, void* d_ws, size_t ws_size,
                              hipStream_t stream) {
    const float* x   = (const float*)d_in[0];
    const int*   ei  = (const int*)d_in[1];   // [2, E]
    const int*   bat = (const int*)d_in[2];
    const float* W1  = (const float*)d_in[3];
    const float* b1  = (const float*)d_in[4];
    const float* W2  = (const float*)d_in[5];
    const float* b2  = (const float*)d_in[6];
    const float* W3  = (const float*)d_in[7];
    const float* b3  = (const float*)d_in[8];
    const float* lw1 = (const float*)d_in[9];
    const float* lb1 = (const float*)d_in[10];
    const float* lw2 = (const float*)d_in[11];
    const float* lb2 = (const float*)d_in[12];
    float* out = (float*)d_out;

    const int* src = ei;
    const int* dst = ei + N_EDGES;

    // workspace carve-up (256B aligned)
    char* ws = (char*)d_ws;
    size_t off = 0;
    auto alloc = [&](size_t bytes) {
        size_t p = off;
        off = (off + bytes + 255) & ~(size_t)255;
        return p;
    };
    float* dinv    = (float*)(ws + alloc(sizeof(float) * N_NODES));
    int*   deg_i   = (int*)  (ws + alloc(sizeof(int) * N_NODES));
    int*   offs    = (int*)  (ws + alloc(sizeof(int) * (N_NODES + 1)));
    int*   bsum    = (int*)  (ws + alloc(sizeof(int) * (SCAN_BLOCKS + 1)));
    int*   bpre    = (int*)  (ws + alloc(sizeof(int) * (SCAN_BLOCKS + 1)));
    int*   rank    = (int*)  (ws + alloc(sizeof(int) * N_EDGES));
    int*   csr_src = (int*)  (ws + alloc(sizeof(int) * N_EDGES));
    float* bufA    = (float*)(ws + alloc(sizeof(float) * (size_t)N_NODES * HIDDEN));
    float* bufB    = (float*)(ws + alloc(sizeof(float) * (size_t)N_NODES * HIDDEN));
    float* pooled  = (float*)(ws + alloc(sizeof(float) * N_GRAPHS * HIDDEN));
    (void)ws_size;

    const int nodeBlocks = (N_NODES + 255) / 256;
    const int edgeBlocks = (N_EDGES + 255) / 256;
    const int mmBlocks   = (N_NODES + 127) / 128;   // 391
    const int aggBlocks  = (N_NODES * 24 + 255) / 256;

    k_init<<<nodeBlocks, 256, 0, stream>>>(deg_i, pooled);
    k_deg<<<edgeBlocks, 256, 0, stream>>>(dst, deg_i, rank);
    k_partial<<<SCAN_BLOCKS, 256, 0, stream>>>(deg_i, bsum);
    k_scanblk<<<1, 256, 0, stream>>>(bsum, bpre);
    k_offs<<<SCAN_BLOCKS, 256, 0, stream>>>(deg_i, bpre, offs, dinv);
    k_fill<<<edgeBlocks, 256, 0, stream>>>(src, dst, rank, offs, csr_src);

    // layer 1: x (K=128)
    k_mm<D_FEAT><<<mmBlocks, 256, 0, stream>>>(x, W1, dinv, bufA);
    k_agg<<<aggBlocks, 256, 0, stream>>>(bufA, dinv, offs, csr_src, b1, bufB);
    // layer 2
    k_mm<HIDDEN><<<mmBlocks, 256, 0, stream>>>(bufB, W2, dinv, bufA);
    k_agg<<<aggBlocks, 256, 0, stream>>>(bufA, dinv, offs, csr_src, b2, bufB);
    // layer 3
    k_mm<HIDDEN><<<mmBlocks, 256, 0, stream>>>(bufB, W3, dinv, bufA);
    k_agg<<<aggBlocks, 256, 0, stream>>>(bufA, dinv, offs, csr_src, b3, bufB);

    k_pool<<<N_GRAPHS * POOL_SLICES, 192, 0, stream>>>(bufB, bat, pooled);
    k_head_mlp<<<N_GRAPHS, 128, 0, stream>>>(pooled, bat, lw1, lb1, lw2, lb2, out);
}